// Round 5
// baseline (171.418 us; speedup 1.0000x reference)
//
#include <hip/hip_runtime.h>
#include <hip/hip_fp16.h>
#include <math.h>

#define SEQ   4096
#define DIM   128
#define UDIM  64
#define BATCH 4
#define BS    (BATCH*SEQ)

typedef _Float16 h8 __attribute__((ext_vector_type(8)));
typedef _Float16 h4 __attribute__((ext_vector_type(4)));
typedef _Float16 h2 __attribute__((ext_vector_type(2)));
typedef float    f4 __attribute__((ext_vector_type(4)));

#define MFMA_K32(a,b,c) __builtin_amdgcn_mfma_f32_16x16x32_f16((a),(b),(c),0,0,0)
#define MFMA_K16(a,b,c) __builtin_amdgcn_mfma_f32_16x16x16f16((a),(b),(c),0,0,0)

__device__ __forceinline__ h2 pk2(float a, float b) {
  return __builtin_bit_cast(h2, __builtin_amdgcn_cvt_pkrtz(a, b));
}

#define WT_STRIDE 272   // proj W^T row stride (136 halves): conflict-free b128
#define VB_STRIDE 144   // proj v-bounce row stride
#define L2E 1.44269504088896f

// ---------------- Kernel A: qkv projection via MFMA (unchanged from R4) ----
__global__ __launch_bounds__(256, 3) void proj_mfma(
    const float* __restrict__ x,
    const float* __restrict__ Wq, const float* __restrict__ bq,
    const float* __restrict__ Wk, const float* __restrict__ bk,
    const float* __restrict__ Wv, const float* __restrict__ bv,
    _Float16* __restrict__ qf, _Float16* __restrict__ kf, _Float16* __restrict__ vt)
{
  const int proj = blockIdx.y;
  const float* __restrict__ W    = proj==0 ? Wq : (proj==1 ? Wk : Wv);
  const float* __restrict__ bias = proj==0 ? bq : (proj==1 ? bk : bv);
  const int tid  = threadIdx.x;
  const int lane = tid & 63, wv = tid >> 6;
  const int n = lane & 15, quad = lane >> 4;
  const int r0 = blockIdx.x * 64;

  __shared__ __align__(16) char lds[UDIM * WT_STRIDE];

  #pragma unroll
  for (int i = 0; i < 8; ++i) {
    const int idx = i*256 + tid;
    const int nn  = idx & 63;
    const int k4  = (idx >> 6) * 4;
    const float w0 = W[(k4+0)*UDIM + nn];
    const float w1 = W[(k4+1)*UDIM + nn];
    const float w2 = W[(k4+2)*UDIM + nn];
    const float w3 = W[(k4+3)*UDIM + nn];
    int2 wd;
    wd.x = __builtin_bit_cast(int, pk2(w0, w1));
    wd.y = __builtin_bit_cast(int, pk2(w2, w3));
    *(int2*)(lds + nn*WT_STRIDE + k4*2) = wd;
  }
  __syncthreads();

  const int row = r0 + wv*16 + n;
  h8 xa[4];
  #pragma unroll
  for (int ks = 0; ks < 4; ++ks) {
    const float* xp = x + (size_t)row*DIM + ks*32 + quad*8;
    const f4 a = *(const f4*)xp, b = *(const f4*)(xp + 4);
    int4 pkd;
    pkd.x = __builtin_bit_cast(int, pk2(a[0], a[1]));
    pkd.y = __builtin_bit_cast(int, pk2(a[2], a[3]));
    pkd.z = __builtin_bit_cast(int, pk2(b[0], b[1]));
    pkd.w = __builtin_bit_cast(int, pk2(b[2], b[3]));
    xa[ks] = __builtin_bit_cast(h8, pkd);
  }

  f4 acc[4];
  #pragma unroll
  for (int nt = 0; nt < 4; ++nt) acc[nt] = (f4){0.f,0.f,0.f,0.f};

  #pragma unroll
  for (int ks = 0; ks < 4; ++ks)
    #pragma unroll
    for (int nt = 0; nt < 4; ++nt) {
      const h8 wf = *(const h8*)(lds + (nt*16 + n)*WT_STRIDE + (ks*32 + quad*8)*2);
      acc[nt] = MFMA_K32(xa[ks], wf, acc[nt]);
    }

  #pragma unroll
  for (int nt = 0; nt < 4; ++nt) {
    const float bb = bias[nt*16 + n];
    #pragma unroll
    for (int r = 0; r < 4; ++r) acc[nt][r] += bb;
  }

  if (proj < 2) {
    _Float16* __restrict__ out = (proj == 0) ? qf : kf;
    const int par = lane & 1;
    const unsigned sel = par ? 0x03020706u : 0x05040100u;
    #pragma unroll
    for (int nt = 0; nt < 4; ++nt)
      #pragma unroll
      for (int p = 0; p < 2; ++p) {
        const int r = 2*p;
        unsigned A  = __builtin_bit_cast(unsigned, pk2(acc[nt][r], acc[nt][r+1]));
        unsigned Bs = (unsigned)__builtin_amdgcn_mov_dpp((int)A, 0xB1, 0xF, 0xF, true);
        unsigned w  = __builtin_amdgcn_perm(Bs, A, sel);
        const int orow = r0 + wv*16 + 4*quad + r + par;
        const int ocol = nt*16 + n - par;
        *(unsigned*)((char*)out + ((size_t)orow*UDIM + ocol)*2) = w;
      }
  } else {
    __syncthreads();
    #pragma unroll
    for (int nt = 0; nt < 4; ++nt)
      #pragma unroll
      for (int p = 0; p < 2; ++p) {
        const int r = 2*p;
        const int u = nt*16 + n;
        const int lrow = wv*16 + 4*quad + r;
        *(unsigned*)(lds + u*VB_STRIDE + lrow*2) =
            __builtin_bit_cast(unsigned, pk2(acc[nt][r], acc[nt][r+1]));
      }
    __syncthreads();
    const int b  = r0 / SEQ;
    const int s0 = r0 % SEQ;
    #pragma unroll
    for (int i = 0; i < 2; ++i) {
      const int e = tid + 256*i;
      const int u = e >> 3, ch = e & 7;
      h8 v = *(const h8*)(lds + u*VB_STRIDE + ch*16);
      *(h8*)(vt + ((size_t)b*UDIM + u)*SEQ + s0 + ch*8) = v;
    }
  }
}

// ---------------- Kernel B: transposed flash attention ----------------
// Barrier-free, zero-LDS. grid (SEQ/128, BATCH, nsplit), block 256 = 4
// independent waves x 32 queries. S^T = K·Q^T so each lane owns a query
// column: softmax state is per-lane scalar; reductions are 2 shfl_xor.
// P^T C-layout == 16x16x16 B-operand layout -> PV (O^T = V^T·P^T) straight
// from registers, no LDS round-trip.
__global__ __launch_bounds__(256, 3) void flash_attn_t(
    const _Float16* __restrict__ qf, const _Float16* __restrict__ kf,
    const _Float16* __restrict__ vt,
    float* __restrict__ opart, float* __restrict__ Mp, float* __restrict__ Lp,
    int nkt)
{
  const int qt = blockIdx.x, b = blockIdx.y, sp = blockIdx.z;
  const _Float16* __restrict__ qb = qf + (size_t)b*SEQ*UDIM;
  const _Float16* __restrict__ kb = kf + (size_t)b*SEQ*UDIM;
  const _Float16* __restrict__ vb = vt + (size_t)b*UDIM*SEQ;

  const int tid = threadIdx.x;
  const int lane = tid & 63, wv = tid >> 6;
  const int n = lane & 15, quad = lane >> 4;
  const int qbase = qt*128 + wv*32;   // this wave's 32 queries

  // Q^T B-frags, persistent: B[k=u=quad*8+j][n=q]
  h8 qB[2][2];
  #pragma unroll
  for (int nt = 0; nt < 2; ++nt)
    #pragma unroll
    for (int ks = 0; ks < 2; ++ks)
      qB[nt][ks] = *(const h8*)(qb + (size_t)(qbase + nt*16 + n)*UDIM + ks*32 + quad*8);

  // O^T accumulators: O[ut][nt], rows u = ut*16+quad*4+r, col q = n
  f4 O[4][2];
  #pragma unroll
  for (int ut = 0; ut < 4; ++ut)
    #pragma unroll
    for (int nt = 0; nt < 2; ++nt) O[ut][nt] = (f4){0.f,0.f,0.f,0.f};

  float M[2] = {-1e30f, -1e30f};
  float Ls[2] = {0.f, 0.f};

  const int kt0 = sp * nkt;
  for (int kt = kt0; kt < kt0 + nkt; ++kt) {
    const int key0 = kt * 64;

    // ---- S^T = K·Q^T : A = K[m=key][k=u], direct from global ----
    f4 S[4][2];
    #pragma unroll
    for (int mt = 0; mt < 4; ++mt)
      #pragma unroll
      for (int nt = 0; nt < 2; ++nt) S[mt][nt] = (f4){0.f,0.f,0.f,0.f};

    #pragma unroll
    for (int ks = 0; ks < 2; ++ks) {
      h8 ka[4];
      #pragma unroll
      for (int mt = 0; mt < 4; ++mt)
        ka[mt] = *(const h8*)(kb + (size_t)(key0 + mt*16 + n)*UDIM + ks*32 + quad*8);
      #pragma unroll
      for (int mt = 0; mt < 4; ++mt)
        #pragma unroll
        for (int nt = 0; nt < 2; ++nt)
          S[mt][nt] = MFMA_K32(ka[mt], qB[nt][ks], S[mt][nt]);
    }

    // ---- online softmax: per-lane query column; 2 shfl_xor reductions ----
    float alpha[2];
    #pragma unroll
    for (int nt = 0; nt < 2; ++nt) {
      float rm = S[0][nt][0];
      #pragma unroll
      for (int mt = 0; mt < 4; ++mt)
        #pragma unroll
        for (int r = 0; r < 4; ++r) rm = fmaxf(rm, S[mt][nt][r]);
      rm = fmaxf(rm, __shfl_xor(rm, 16));
      rm = fmaxf(rm, __shfl_xor(rm, 32));
      const float mo = M[nt];
      const float mn = fmaxf(mo, rm);
      alpha[nt] = exp2f((mo - mn) * L2E);
      const float mnl = mn * L2E;
      float rs = 0.f;
      #pragma unroll
      for (int mt = 0; mt < 4; ++mt)
        #pragma unroll
        for (int r = 0; r < 4; ++r) {
          const float p = exp2f(fmaf(S[mt][nt][r], L2E, -mnl));
          S[mt][nt][r] = p;
          rs += p;
        }
      rs += __shfl_xor(rs, 16);
      rs += __shfl_xor(rs, 32);
      M[nt]  = mn;
      Ls[nt] = Ls[nt] * alpha[nt] + rs;
      #pragma unroll
      for (int ut = 0; ut < 4; ++ut)
        #pragma unroll
        for (int r = 0; r < 4; ++r) O[ut][nt][r] *= alpha[nt];
    }

    // ---- pack P^T: C-layout regs ARE the K16 B-frag (k=quad*4+j) ----
    h4 pB[4][2];
    #pragma unroll
    for (int mt = 0; mt < 4; ++mt)
      #pragma unroll
      for (int nt = 0; nt < 2; ++nt) {
        int2 t;
        t.x = __builtin_bit_cast(int, pk2(S[mt][nt][0], S[mt][nt][1]));
        t.y = __builtin_bit_cast(int, pk2(S[mt][nt][2], S[mt][nt][3]));
        pB[mt][nt] = __builtin_bit_cast(h4, t);
      }

    // ---- O^T += V^T·P^T : A = V^T[m=u][k=key], direct from global ----
    #pragma unroll
    for (int mt = 0; mt < 4; ++mt) {
      h4 va[4];
      #pragma unroll
      for (int ut = 0; ut < 4; ++ut)
        va[ut] = *(const h4*)(vb + (size_t)(ut*16 + n)*SEQ + key0 + mt*16 + quad*4);
      #pragma unroll
      for (int ut = 0; ut < 4; ++ut)
        #pragma unroll
        for (int nt = 0; nt < 2; ++nt)
          O[ut][nt] = MFMA_K16(va[ut], pB[mt][nt], O[ut][nt]);
    }
  }

  // ---- epilogue: direct scatter stores (L2 merges partial lines) ----
  const size_t rowg = (size_t)sp*BS + (size_t)b*SEQ + qbase;
  #pragma unroll
  for (int nt = 0; nt < 2; ++nt) {
    float* __restrict__ orow = opart + (rowg + nt*16 + n)*UDIM;
    #pragma unroll
    for (int ut = 0; ut < 4; ++ut)
      #pragma unroll
      for (int r = 0; r < 4; ++r)
        orow[ut*16 + quad*4 + r] = O[ut][nt][r];
    if (quad == 0) {
      Mp[rowg + nt*16 + n] = M[nt] * L2E;   // log2 domain
      Lp[rowg + nt*16 + n] = Ls[nt];
    }
  }
}

// ---------------- Kernel C: merge key-split partials (f4) ----------------
__global__ __launch_bounds__(256) void merge_out(
    const float* __restrict__ opart, const float* __restrict__ Mp,
    const float* __restrict__ Lp, float* __restrict__ out, int nsplit)
{
  const int tid = threadIdx.x;
  const int row = blockIdx.x*16 + (tid >> 4);
  const int u4  = (tid & 15) * 4;
  float M = -1e30f;
  for (int s = 0; s < nsplit; ++s) M = fmaxf(M, Mp[(size_t)s*BS + row]);
  f4 num = (f4){0.f,0.f,0.f,0.f};
  float den = 0.f;
  for (int s = 0; s < nsplit; ++s) {
    const float w = exp2f(Mp[(size_t)s*BS + row] - M);
    den += w * Lp[(size_t)s*BS + row];
    const f4 op = *(const f4*)(opart + ((size_t)s*BS + row)*UDIM + u4);
    num += w * op;
  }
  const float dinv = 1.f / den;
  *(f4*)(out + (size_t)row*UDIM + u4) = num * dinv;
}

extern "C" void kernel_launch(void* const* d_in, const int* in_sizes, int n_in,
                              void* d_out, int out_size, void* d_ws, size_t ws_size,
                              hipStream_t stream) {
  (void)in_sizes; (void)n_in; (void)out_size;
  const float* x  = (const float*)d_in[0];
  const float* Wq = (const float*)d_in[1];
  const float* bq = (const float*)d_in[2];
  const float* Wk = (const float*)d_in[3];
  const float* bk = (const float*)d_in[4];
  const float* Wv = (const float*)d_in[5];
  const float* bv = (const float*)d_in[6];
  float* out = (float*)d_out;

  char* ws = (char*)d_ws;
  const size_t fBytes = (size_t)BS * UDIM * 2;
  auto need = [](int nsp) {
    return (size_t)3*BS*UDIM*2 + (size_t)nsp*BS*4*2 + (size_t)nsp*BS*UDIM*4;
  };
  int nsplit;
  if      (ws_size >= need(8)) nsplit = 8;
  else if (ws_size >= need(4)) nsplit = 4;
  else if (ws_size >= need(2)) nsplit = 2;
  else                         nsplit = 1;

  _Float16* qf = (_Float16*)(ws);
  _Float16* kf = (_Float16*)(ws + fBytes);
  _Float16* vt = (_Float16*)(ws + 2*fBytes);
  float* Mp    = (float*)(ws + 3*fBytes);
  float* Lp    = (float*)(ws + 3*fBytes + (size_t)nsplit*BS*4);
  float* opart = (float*)(ws + 3*fBytes + (size_t)nsplit*BS*8);

  proj_mfma<<<dim3(BS/64, 3), 256, 0, stream>>>(x, Wq, bq, Wk, bk, Wv, bv, qf, kf, vt);
  flash_attn_t<<<dim3(SEQ/128, BATCH, nsplit), 256, 0, stream>>>(
      qf, kf, vt, opart, Mp, Lp, (SEQ/64)/nsplit);
  merge_out<<<dim3(BS/16), 256, 0, stream>>>(opart, Mp, Lp, out, nsplit);
}

// Round 6
// 123.095 us; speedup vs baseline: 1.3926x; 1.3926x over previous
//
#include <hip/hip_runtime.h>
#include <hip/hip_fp16.h>
#include <math.h>

#define SEQ   4096
#define DIM   128
#define UDIM  64
#define BATCH 4
#define BS    (BATCH*SEQ)

typedef _Float16 h8 __attribute__((ext_vector_type(8)));
typedef _Float16 h4 __attribute__((ext_vector_type(4)));
typedef _Float16 h2 __attribute__((ext_vector_type(2)));
typedef float    f4 __attribute__((ext_vector_type(4)));

#define MFMA_K32(a,b,c) __builtin_amdgcn_mfma_f32_16x16x32_f16((a),(b),(c),0,0,0)
#define MFMA_K16(a,b,c) __builtin_amdgcn_mfma_f32_16x16x16f16((a),(b),(c),0,0,0)

__device__ __forceinline__ h2 pk2(float a, float b) {
  return __builtin_bit_cast(h2, __builtin_amdgcn_cvt_pkrtz(a, b));
}

#define WT_STRIDE 272   // proj W^T row stride (136 halves): conflict-free b128
#define VB_STRIDE 144   // 72-half row stride: 36 words ≡ 4 (mod 32) -> ≤2-way (free)
#define L2E 1.44269504088896f

// ---------------- Kernel A: qkv projection via MFMA (unchanged) ----------
__global__ __launch_bounds__(256, 3) void proj_mfma(
    const float* __restrict__ x,
    const float* __restrict__ Wq, const float* __restrict__ bq,
    const float* __restrict__ Wk, const float* __restrict__ bk,
    const float* __restrict__ Wv, const float* __restrict__ bv,
    _Float16* __restrict__ qf, _Float16* __restrict__ kf, _Float16* __restrict__ vt)
{
  const int proj = blockIdx.y;
  const float* __restrict__ W    = proj==0 ? Wq : (proj==1 ? Wk : Wv);
  const float* __restrict__ bias = proj==0 ? bq : (proj==1 ? bk : bv);
  const int tid  = threadIdx.x;
  const int lane = tid & 63, wv = tid >> 6;
  const int n = lane & 15, quad = lane >> 4;
  const int r0 = blockIdx.x * 64;

  __shared__ __align__(16) char lds[UDIM * WT_STRIDE];

  #pragma unroll
  for (int i = 0; i < 8; ++i) {
    const int idx = i*256 + tid;
    const int nn  = idx & 63;
    const int k4  = (idx >> 6) * 4;
    const float w0 = W[(k4+0)*UDIM + nn];
    const float w1 = W[(k4+1)*UDIM + nn];
    const float w2 = W[(k4+2)*UDIM + nn];
    const float w3 = W[(k4+3)*UDIM + nn];
    int2 wd;
    wd.x = __builtin_bit_cast(int, pk2(w0, w1));
    wd.y = __builtin_bit_cast(int, pk2(w2, w3));
    *(int2*)(lds + nn*WT_STRIDE + k4*2) = wd;
  }
  __syncthreads();

  const int row = r0 + wv*16 + n;
  h8 xa[4];
  #pragma unroll
  for (int ks = 0; ks < 4; ++ks) {
    const float* xp = x + (size_t)row*DIM + ks*32 + quad*8;
    const f4 a = *(const f4*)xp, b = *(const f4*)(xp + 4);
    int4 pkd;
    pkd.x = __builtin_bit_cast(int, pk2(a[0], a[1]));
    pkd.y = __builtin_bit_cast(int, pk2(a[2], a[3]));
    pkd.z = __builtin_bit_cast(int, pk2(b[0], b[1]));
    pkd.w = __builtin_bit_cast(int, pk2(b[2], b[3]));
    xa[ks] = __builtin_bit_cast(h8, pkd);
  }

  f4 acc[4];
  #pragma unroll
  for (int nt = 0; nt < 4; ++nt) acc[nt] = (f4){0.f,0.f,0.f,0.f};

  #pragma unroll
  for (int ks = 0; ks < 4; ++ks)
    #pragma unroll
    for (int nt = 0; nt < 4; ++nt) {
      const h8 wf = *(const h8*)(lds + (nt*16 + n)*WT_STRIDE + (ks*32 + quad*8)*2);
      acc[nt] = MFMA_K32(xa[ks], wf, acc[nt]);
    }

  #pragma unroll
  for (int nt = 0; nt < 4; ++nt) {
    const float bb = bias[nt*16 + n];
    #pragma unroll
    for (int r = 0; r < 4; ++r) acc[nt][r] += bb;
  }

  if (proj < 2) {
    _Float16* __restrict__ out = (proj == 0) ? qf : kf;
    const int par = lane & 1;
    const unsigned sel = par ? 0x03020706u : 0x05040100u;
    #pragma unroll
    for (int nt = 0; nt < 4; ++nt)
      #pragma unroll
      for (int p = 0; p < 2; ++p) {
        const int r = 2*p;
        unsigned A  = __builtin_bit_cast(unsigned, pk2(acc[nt][r], acc[nt][r+1]));
        unsigned Bs = (unsigned)__builtin_amdgcn_mov_dpp((int)A, 0xB1, 0xF, 0xF, true);
        unsigned w  = __builtin_amdgcn_perm(Bs, A, sel);
        const int orow = r0 + wv*16 + 4*quad + r + par;
        const int ocol = nt*16 + n - par;
        *(unsigned*)((char*)out + ((size_t)orow*UDIM + ocol)*2) = w;
      }
  } else {
    __syncthreads();
    #pragma unroll
    for (int nt = 0; nt < 4; ++nt)
      #pragma unroll
      for (int p = 0; p < 2; ++p) {
        const int r = 2*p;
        const int u = nt*16 + n;
        const int lrow = wv*16 + 4*quad + r;
        *(unsigned*)(lds + u*VB_STRIDE + lrow*2) =
            __builtin_bit_cast(unsigned, pk2(acc[nt][r], acc[nt][r+1]));
      }
    __syncthreads();
    const int b  = r0 / SEQ;
    const int s0 = r0 % SEQ;
    #pragma unroll
    for (int i = 0; i < 2; ++i) {
      const int e = tid + 256*i;
      const int u = e >> 3, ch = e & 7;
      h8 v = *(const h8*)(lds + u*VB_STRIDE + ch*16);
      *(h8*)(vt + ((size_t)b*UDIM + u)*SEQ + s0 + ch*8) = v;
    }
  }
}

// ---------------- Kernel B: transposed flash attention + LDS tiles ------
// grid (SEQ/128, BATCH, nsplit), block 256 = 4 waves x 32 queries.
// S^T = K·Q^T (lane owns a query column: scalar softmax state, 2 shfl_xor);
// P^T C-layout == K16 B-operand layout -> PV from registers.
// K[key][u] and V^T[u][key] tiles staged in LDS via straight coalesced
// copies (no transpose); frag reads conflict-free at stride 144.
__global__ __launch_bounds__(256, 3) void flash_attn_t(
    const _Float16* __restrict__ qf, const _Float16* __restrict__ kf,
    const _Float16* __restrict__ vt,
    _Float16* __restrict__ opart, float* __restrict__ Mp, float* __restrict__ Lp,
    int nkt)
{
  const int qt = blockIdx.x, b = blockIdx.y, sp = blockIdx.z;
  const _Float16* __restrict__ qb = qf + (size_t)b*SEQ*UDIM;
  const _Float16* __restrict__ kb = kf + (size_t)b*SEQ*UDIM;
  const _Float16* __restrict__ vb = vt + (size_t)b*UDIM*SEQ;

  __shared__ __align__(16) char Ks[64 * VB_STRIDE];  // K[key][u]   9216 B
  __shared__ __align__(16) char Vs[64 * VB_STRIDE];  // V^T[u][key] 9216 B

  const int tid = threadIdx.x;
  const int lane = tid & 63, wv = tid >> 6;
  const int n = lane & 15, quad = lane >> 4;
  const int qbase = qt*128 + wv*32;

  // Q^T B-frags, persistent: B[k=u=quad*8+j][n=q]
  h8 qB[2][2];
  #pragma unroll
  for (int nt = 0; nt < 2; ++nt)
    #pragma unroll
    for (int ks = 0; ks < 2; ++ks)
      qB[nt][ks] = *(const h8*)(qb + (size_t)(qbase + nt*16 + n)*UDIM + ks*32 + quad*8);

  f4 O[4][2];
  #pragma unroll
  for (int ut = 0; ut < 4; ++ut)
    #pragma unroll
    for (int nt = 0; nt < 2; ++nt) O[ut][nt] = (f4){0.f,0.f,0.f,0.f};

  float M[2] = {-1e30f, -1e30f};
  float Ls[2] = {0.f, 0.f};

  // staging source pointers (advance by 64 keys per kt)
  const int e4a = tid, e4b = tid + 256;           // h8 indices 0..511
  const _Float16* kga = kb + ((size_t)(sp*nkt)*64 + (e4a>>3))*UDIM + (e4a&7)*8;
  const _Float16* kgb = kb + ((size_t)(sp*nkt)*64 + (e4b>>3))*UDIM + (e4b&7)*8;
  const _Float16* vga = vb + (size_t)(e4a>>3)*SEQ + sp*nkt*64 + (e4a&7)*8;
  const _Float16* vgb = vb + (size_t)(e4b>>3)*SEQ + sp*nkt*64 + (e4b&7)*8;
  char* kda = Ks + (e4a>>3)*VB_STRIDE + (e4a&7)*16;
  char* kdb = Ks + (e4b>>3)*VB_STRIDE + (e4b&7)*16;
  char* vda = Vs + (e4a>>3)*VB_STRIDE + (e4a&7)*16;
  char* vdb = Vs + (e4b>>3)*VB_STRIDE + (e4b&7)*16;

  for (int kt = 0; kt < nkt; ++kt) {
    __syncthreads();   // protect tiles from previous iteration's readers
    *(h8*)kda = *(const h8*)kga;  kga += (size_t)64*UDIM;
    *(h8*)kdb = *(const h8*)kgb;  kgb += (size_t)64*UDIM;
    *(h8*)vda = *(const h8*)vga;  vga += 64;
    *(h8*)vdb = *(const h8*)vgb;  vgb += 64;
    __syncthreads();

    // ---- S^T = K·Q^T : A-frags from LDS (b128, conflict-free) ----
    f4 S[4][2];
    #pragma unroll
    for (int mt = 0; mt < 4; ++mt)
      #pragma unroll
      for (int nt = 0; nt < 2; ++nt) S[mt][nt] = (f4){0.f,0.f,0.f,0.f};

    #pragma unroll
    for (int ks = 0; ks < 2; ++ks) {
      h8 ka[4];
      #pragma unroll
      for (int mt = 0; mt < 4; ++mt)
        ka[mt] = *(const h8*)(Ks + (mt*16 + n)*VB_STRIDE + ks*64 + quad*16);
      #pragma unroll
      for (int mt = 0; mt < 4; ++mt)
        #pragma unroll
        for (int nt = 0; nt < 2; ++nt)
          S[mt][nt] = MFMA_K32(ka[mt], qB[nt][ks], S[mt][nt]);
    }

    // ---- online softmax: per-lane query column ----
    float alpha[2];
    #pragma unroll
    for (int nt = 0; nt < 2; ++nt) {
      float rm = S[0][nt][0];
      #pragma unroll
      for (int mt = 0; mt < 4; ++mt)
        #pragma unroll
        for (int r = 0; r < 4; ++r) rm = fmaxf(rm, S[mt][nt][r]);
      rm = fmaxf(rm, __shfl_xor(rm, 16));
      rm = fmaxf(rm, __shfl_xor(rm, 32));
      const float mo = M[nt];
      const float mn = fmaxf(mo, rm);
      alpha[nt] = exp2f((mo - mn) * L2E);
      const float mnl = mn * L2E;
      float rs = 0.f;
      #pragma unroll
      for (int mt = 0; mt < 4; ++mt)
        #pragma unroll
        for (int r = 0; r < 4; ++r) {
          const float p = exp2f(fmaf(S[mt][nt][r], L2E, -mnl));
          S[mt][nt][r] = p;
          rs += p;
        }
      rs += __shfl_xor(rs, 16);
      rs += __shfl_xor(rs, 32);
      M[nt]  = mn;
      Ls[nt] = Ls[nt] * alpha[nt] + rs;
      #pragma unroll
      for (int ut = 0; ut < 4; ++ut)
        #pragma unroll
        for (int r = 0; r < 4; ++r) O[ut][nt][r] *= alpha[nt];
    }

    // ---- pack P^T: C-layout regs ARE the K16 B-frag (k=quad*4+j) ----
    h4 pB[4][2];
    #pragma unroll
    for (int mt = 0; mt < 4; ++mt)
      #pragma unroll
      for (int nt = 0; nt < 2; ++nt) {
        int2 t;
        t.x = __builtin_bit_cast(int, pk2(S[mt][nt][0], S[mt][nt][1]));
        t.y = __builtin_bit_cast(int, pk2(S[mt][nt][2], S[mt][nt][3]));
        pB[mt][nt] = __builtin_bit_cast(h4, t);
      }

    // ---- O^T += V^T·P^T : A-frags from LDS (b64, conflict-free) ----
    #pragma unroll
    for (int mt = 0; mt < 4; ++mt) {
      h4 va[4];
      #pragma unroll
      for (int ut = 0; ut < 4; ++ut)
        va[ut] = *(const h4*)(Vs + (ut*16 + n)*VB_STRIDE + mt*32 + quad*8);
      #pragma unroll
      for (int ut = 0; ut < 4; ++ut)
        #pragma unroll
        for (int nt = 0; nt < 2; ++nt)
          O[ut][nt] = MFMA_K16(va[ut], pB[mt][nt], O[ut][nt]);
    }
  }

  // ---- epilogue: f16 partials, b32 pair-packed stores ----
  const size_t rowg = (size_t)sp*BS + (size_t)b*SEQ + qbase;
  #pragma unroll
  for (int nt = 0; nt < 2; ++nt) {
    char* __restrict__ orow = (char*)(opart + (rowg + nt*16 + n)*UDIM);
    #pragma unroll
    for (int ut = 0; ut < 4; ++ut)
      #pragma unroll
      for (int p = 0; p < 2; ++p)
        *(unsigned*)(orow + (ut*16 + quad*4 + 2*p)*2) =
            __builtin_bit_cast(unsigned, pk2(O[ut][nt][2*p], O[ut][nt][2*p+1]));
    if (quad == 0) {
      Mp[rowg + nt*16 + n] = M[nt] * L2E;   // log2 domain
      Lp[rowg + nt*16 + n] = Ls[nt];
    }
  }
}

// ---------------- Kernel C: merge key-split partials ----------------
__global__ __launch_bounds__(256) void merge_out(
    const _Float16* __restrict__ opart, const float* __restrict__ Mp,
    const float* __restrict__ Lp, float* __restrict__ out, int nsplit)
{
  const int tid = threadIdx.x;
  const int row = blockIdx.x*16 + (tid >> 4);
  const int u4  = (tid & 15) * 4;
  float M = -1e30f;
  for (int s = 0; s < nsplit; ++s) M = fmaxf(M, Mp[(size_t)s*BS + row]);
  f4 num = (f4){0.f,0.f,0.f,0.f};
  float den = 0.f;
  for (int s = 0; s < nsplit; ++s) {
    const float w = exp2f(Mp[(size_t)s*BS + row] - M);
    den += w * Lp[(size_t)s*BS + row];
    const h4 op = *(const h4*)(opart + ((size_t)s*BS + row)*UDIM + u4);
    #pragma unroll
    for (int i = 0; i < 4; ++i) num[i] += w * (float)op[i];
  }
  const float dinv = 1.f / den;
  *(f4*)(out + (size_t)row*UDIM + u4) = num * dinv;
}

extern "C" void kernel_launch(void* const* d_in, const int* in_sizes, int n_in,
                              void* d_out, int out_size, void* d_ws, size_t ws_size,
                              hipStream_t stream) {
  (void)in_sizes; (void)n_in; (void)out_size;
  const float* x  = (const float*)d_in[0];
  const float* Wq = (const float*)d_in[1];
  const float* bq = (const float*)d_in[2];
  const float* Wk = (const float*)d_in[3];
  const float* bk = (const float*)d_in[4];
  const float* Wv = (const float*)d_in[5];
  const float* bv = (const float*)d_in[6];
  float* out = (float*)d_out;

  char* ws = (char*)d_ws;
  const size_t fBytes = (size_t)BS * UDIM * 2;
  auto need = [](int nsp) {   // qkv f16 + Mp/Lp f32 + opart f16
    return (size_t)3*BS*UDIM*2 + (size_t)nsp*BS*4*2 + (size_t)nsp*BS*UDIM*2;
  };
  int nsplit;
  if      (ws_size >= need(8)) nsplit = 8;
  else if (ws_size >= need(4)) nsplit = 4;
  else if (ws_size >= need(2)) nsplit = 2;
  else                         nsplit = 1;

  _Float16* qf = (_Float16*)(ws);
  _Float16* kf = (_Float16*)(ws + fBytes);
  _Float16* vt = (_Float16*)(ws + 2*fBytes);
  float* Mp    = (float*)(ws + 3*fBytes);
  float* Lp    = (float*)(ws + 3*fBytes + (size_t)nsplit*BS*4);
  _Float16* opart = (_Float16*)(ws + 3*fBytes + (size_t)nsplit*BS*8);

  proj_mfma<<<dim3(BS/64, 3), 256, 0, stream>>>(x, Wq, bq, Wk, bk, Wv, bv, qf, kf, vt);
  flash_attn_t<<<dim3(SEQ/128, BATCH, nsplit), 256, 0, stream>>>(
      qf, kf, vt, opart, Mp, Lp, (SEQ/64)/nsplit);
  merge_out<<<dim3(BS/16), 256, 0, stream>>>(opart, Mp, Lp, out, nsplit);
}

// Round 7
// 121.063 us; speedup vs baseline: 1.4159x; 1.0168x over previous
//
#include <hip/hip_runtime.h>
#include <hip/hip_fp16.h>
#include <math.h>

#define SEQ   4096
#define DIM   128
#define UDIM  64
#define BATCH 4
#define BS    (BATCH*SEQ)

typedef _Float16 h8 __attribute__((ext_vector_type(8)));
typedef _Float16 h4 __attribute__((ext_vector_type(4)));
typedef _Float16 h2 __attribute__((ext_vector_type(2)));
typedef float    f4 __attribute__((ext_vector_type(4)));

#define MFMA_K32(a,b,c) __builtin_amdgcn_mfma_f32_16x16x32_f16((a),(b),(c),0,0,0)
#define MFMA_K16(a,b,c) __builtin_amdgcn_mfma_f32_16x16x16f16((a),(b),(c),0,0,0)

__device__ __forceinline__ h2 pk2(float a, float b) {
  return __builtin_bit_cast(h2, __builtin_amdgcn_cvt_pkrtz(a, b));
}

#define WT_STRIDE 272   // proj W^T row stride (136 halves): conflict-free b128
#define VB_STRIDE 144   // 72-half row stride: 36 words ≡ 4 (mod 32) -> ≤2-way (free)
#define L2E 1.44269504088896f

// ---------------- Kernel A: qkv projection via MFMA (unchanged) ----------
__global__ __launch_bounds__(256, 3) void proj_mfma(
    const float* __restrict__ x,
    const float* __restrict__ Wq, const float* __restrict__ bq,
    const float* __restrict__ Wk, const float* __restrict__ bk,
    const float* __restrict__ Wv, const float* __restrict__ bv,
    _Float16* __restrict__ qf, _Float16* __restrict__ kf, _Float16* __restrict__ vt)
{
  const int proj = blockIdx.y;
  const float* __restrict__ W    = proj==0 ? Wq : (proj==1 ? Wk : Wv);
  const float* __restrict__ bias = proj==0 ? bq : (proj==1 ? bk : bv);
  const int tid  = threadIdx.x;
  const int lane = tid & 63, wv = tid >> 6;
  const int n = lane & 15, quad = lane >> 4;
  const int r0 = blockIdx.x * 64;

  __shared__ __align__(16) char lds[UDIM * WT_STRIDE];

  #pragma unroll
  for (int i = 0; i < 8; ++i) {
    const int idx = i*256 + tid;
    const int nn  = idx & 63;
    const int k4  = (idx >> 6) * 4;
    const float w0 = W[(k4+0)*UDIM + nn];
    const float w1 = W[(k4+1)*UDIM + nn];
    const float w2 = W[(k4+2)*UDIM + nn];
    const float w3 = W[(k4+3)*UDIM + nn];
    int2 wd;
    wd.x = __builtin_bit_cast(int, pk2(w0, w1));
    wd.y = __builtin_bit_cast(int, pk2(w2, w3));
    *(int2*)(lds + nn*WT_STRIDE + k4*2) = wd;
  }
  __syncthreads();

  const int row = r0 + wv*16 + n;
  h8 xa[4];
  #pragma unroll
  for (int ks = 0; ks < 4; ++ks) {
    const float* xp = x + (size_t)row*DIM + ks*32 + quad*8;
    const f4 a = *(const f4*)xp, b = *(const f4*)(xp + 4);
    int4 pkd;
    pkd.x = __builtin_bit_cast(int, pk2(a[0], a[1]));
    pkd.y = __builtin_bit_cast(int, pk2(a[2], a[3]));
    pkd.z = __builtin_bit_cast(int, pk2(b[0], b[1]));
    pkd.w = __builtin_bit_cast(int, pk2(b[2], b[3]));
    xa[ks] = __builtin_bit_cast(h8, pkd);
  }

  f4 acc[4];
  #pragma unroll
  for (int nt = 0; nt < 4; ++nt) acc[nt] = (f4){0.f,0.f,0.f,0.f};

  #pragma unroll
  for (int ks = 0; ks < 4; ++ks)
    #pragma unroll
    for (int nt = 0; nt < 4; ++nt) {
      const h8 wf = *(const h8*)(lds + (nt*16 + n)*WT_STRIDE + (ks*32 + quad*8)*2);
      acc[nt] = MFMA_K32(xa[ks], wf, acc[nt]);
    }

  #pragma unroll
  for (int nt = 0; nt < 4; ++nt) {
    const float bb = bias[nt*16 + n];
    #pragma unroll
    for (int r = 0; r < 4; ++r) acc[nt][r] += bb;
  }

  if (proj < 2) {
    _Float16* __restrict__ out = (proj == 0) ? qf : kf;
    const int par = lane & 1;
    const unsigned sel = par ? 0x03020706u : 0x05040100u;
    #pragma unroll
    for (int nt = 0; nt < 4; ++nt)
      #pragma unroll
      for (int p = 0; p < 2; ++p) {
        const int r = 2*p;
        unsigned A  = __builtin_bit_cast(unsigned, pk2(acc[nt][r], acc[nt][r+1]));
        unsigned Bs = (unsigned)__builtin_amdgcn_mov_dpp((int)A, 0xB1, 0xF, 0xF, true);
        unsigned w  = __builtin_amdgcn_perm(Bs, A, sel);
        const int orow = r0 + wv*16 + 4*quad + r + par;
        const int ocol = nt*16 + n - par;
        *(unsigned*)((char*)out + ((size_t)orow*UDIM + ocol)*2) = w;
      }
  } else {
    __syncthreads();
    #pragma unroll
    for (int nt = 0; nt < 4; ++nt)
      #pragma unroll
      for (int p = 0; p < 2; ++p) {
        const int r = 2*p;
        const int u = nt*16 + n;
        const int lrow = wv*16 + 4*quad + r;
        *(unsigned*)(lds + u*VB_STRIDE + lrow*2) =
            __builtin_bit_cast(unsigned, pk2(acc[nt][r], acc[nt][r+1]));
      }
    __syncthreads();
    const int b  = r0 / SEQ;
    const int s0 = r0 % SEQ;
    #pragma unroll
    for (int i = 0; i < 2; ++i) {
      const int e = tid + 256*i;
      const int u = e >> 3, ch = e & 7;
      h8 v = *(const h8*)(lds + u*VB_STRIDE + ch*16);
      *(h8*)(vt + ((size_t)b*UDIM + u)*SEQ + s0 + ch*8) = v;
    }
  }
}

// ---------------- Kernel B: pipelined transposed flash attention --------
// grid (SEQ/128, BATCH, nsplit), block 256 = 4 waves x 32 queries.
// S^T = K·Q^T; P^T C-layout == K16 B-operand -> PV from registers.
// Pipeline: register-prefetch tile kt+1 globals BEFORE computing kt;
// double-buffered LDS -> one barrier/iter, no VMEM latency inside it.
// l carried as a ones-row MFMA accumulator (no sum shuffles).
__global__ __launch_bounds__(256, 3) void flash_attn_t(
    const _Float16* __restrict__ qf, const _Float16* __restrict__ kf,
    const _Float16* __restrict__ vt,
    _Float16* __restrict__ opart, float* __restrict__ Mp, float* __restrict__ Lp,
    int nkt)
{
  const int qt = blockIdx.x, b = blockIdx.y, sp = blockIdx.z;
  const _Float16* __restrict__ qb = qf + (size_t)b*SEQ*UDIM;
  const _Float16* __restrict__ kb = kf + (size_t)b*SEQ*UDIM;
  const _Float16* __restrict__ vb = vt + (size_t)b*UDIM*SEQ;

  __shared__ __align__(16) char Ks[2][64 * VB_STRIDE];  // K[key][u]
  __shared__ __align__(16) char Vs[2][64 * VB_STRIDE];  // V^T[u][key]

  const int tid = threadIdx.x;
  const int lane = tid & 63, wv = tid >> 6;
  const int n = lane & 15, quad = lane >> 4;
  const int qbase = qt*128 + wv*32;

  // Q^T B-frags, persistent
  h8 qB[2][2];
  #pragma unroll
  for (int nt = 0; nt < 2; ++nt)
    #pragma unroll
    for (int ks = 0; ks < 2; ++ks)
      qB[nt][ks] = *(const h8*)(qb + (size_t)(qbase + nt*16 + n)*UDIM + ks*32 + quad*8);

  f4 O[4][2], Ol[2];
  #pragma unroll
  for (int ut = 0; ut < 4; ++ut)
    #pragma unroll
    for (int nt = 0; nt < 2; ++nt) O[ut][nt] = (f4){0.f,0.f,0.f,0.f};
  Ol[0] = (f4){0.f,0.f,0.f,0.f};
  Ol[1] = (f4){0.f,0.f,0.f,0.f};

  float M[2] = {-1e30f, -1e30f};

  h4 ones_a;
  { const _Float16 o = (_Float16)1.0f;
    ones_a[0]=o; ones_a[1]=o; ones_a[2]=o; ones_a[3]=o; }

  // staging decomposition: thread covers h8 elements e0 and e0+256
  const int e0 = tid, e1 = tid + 256;
  const _Float16* kg0 = kb + ((size_t)sp*nkt*64 + (e0>>3))*UDIM + (e0&7)*8;
  const _Float16* kg1 = kb + ((size_t)sp*nkt*64 + (e1>>3))*UDIM + (e1&7)*8;
  const _Float16* vg0 = vb + (size_t)(e0>>3)*SEQ + sp*nkt*64 + (e0&7)*8;
  const _Float16* vg1 = vb + (size_t)(e1>>3)*SEQ + sp*nkt*64 + (e1&7)*8;
  const int kofs0 = (e0>>3)*VB_STRIDE + (e0&7)*16;
  const int kofs1 = (e1>>3)*VB_STRIDE + (e1&7)*16;

  // prime tile 0
  h8 pk0 = *(const h8*)kg0, pk1 = *(const h8*)kg1;
  h8 pv0 = *(const h8*)vg0, pv1 = *(const h8*)vg1;
  *(h8*)(Ks[0]+kofs0) = pk0;  *(h8*)(Ks[0]+kofs1) = pk1;
  *(h8*)(Vs[0]+kofs0) = pv0;  *(h8*)(Vs[0]+kofs1) = pv1;
  __syncthreads();

  for (int kt = 0; kt < nkt; ++kt) {
    const int cur = kt & 1;
    const bool more = (kt + 1 < nkt);
    const char* __restrict__ Kc = Ks[cur];
    const char* __restrict__ Vc = Vs[cur];

    // ---- prefetch tile kt+1 (no wait; latency covered by compute) ----
    if (more) {
      kg0 += (size_t)64*UDIM;  kg1 += (size_t)64*UDIM;
      vg0 += 64;               vg1 += 64;
      pk0 = *(const h8*)kg0;   pk1 = *(const h8*)kg1;
      pv0 = *(const h8*)vg0;   pv1 = *(const h8*)vg1;
    }

    // ---- S^T = K·Q^T ----
    f4 S[4][2];
    #pragma unroll
    for (int mt = 0; mt < 4; ++mt)
      #pragma unroll
      for (int nt = 0; nt < 2; ++nt) S[mt][nt] = (f4){0.f,0.f,0.f,0.f};

    #pragma unroll
    for (int ks = 0; ks < 2; ++ks) {
      h8 ka[4];
      #pragma unroll
      for (int mt = 0; mt < 4; ++mt)
        ka[mt] = *(const h8*)(Kc + (mt*16 + n)*VB_STRIDE + ks*64 + quad*16);
      #pragma unroll
      for (int mt = 0; mt < 4; ++mt)
        #pragma unroll
        for (int nt = 0; nt < 2; ++nt)
          S[mt][nt] = MFMA_K32(ka[mt], qB[nt][ks], S[mt][nt]);
    }

    // ---- online softmax (max only; l via ones-row MFMA) ----
    float alpha[2];
    #pragma unroll
    for (int nt = 0; nt < 2; ++nt) {
      float rm = S[0][nt][0];
      #pragma unroll
      for (int mt = 0; mt < 4; ++mt)
        #pragma unroll
        for (int r = 0; r < 4; ++r) rm = fmaxf(rm, S[mt][nt][r]);
      rm = fmaxf(rm, __shfl_xor(rm, 16));
      rm = fmaxf(rm, __shfl_xor(rm, 32));
      const float mo = M[nt];
      const float mn = fmaxf(mo, rm);
      alpha[nt] = exp2f((mo - mn) * L2E);
      const float mnl = mn * L2E;
      #pragma unroll
      for (int mt = 0; mt < 4; ++mt)
        #pragma unroll
        for (int r = 0; r < 4; ++r)
          S[mt][nt][r] = exp2f(fmaf(S[mt][nt][r], L2E, -mnl));
      M[nt] = mn;
      #pragma unroll
      for (int ut = 0; ut < 4; ++ut)
        #pragma unroll
        for (int r = 0; r < 4; ++r) O[ut][nt][r] *= alpha[nt];
      #pragma unroll
      for (int r = 0; r < 4; ++r) Ol[nt][r] *= alpha[nt];
    }

    // ---- pack P^T: C-layout regs ARE the K16 B-frag ----
    h4 pB[4][2];
    #pragma unroll
    for (int mt = 0; mt < 4; ++mt)
      #pragma unroll
      for (int nt = 0; nt < 2; ++nt) {
        int2 t;
        t.x = __builtin_bit_cast(int, pk2(S[mt][nt][0], S[mt][nt][1]));
        t.y = __builtin_bit_cast(int, pk2(S[mt][nt][2], S[mt][nt][3]));
        pB[mt][nt] = __builtin_bit_cast(h4, t);
      }

    // ---- O^T += V^T·P^T ; l-row += ones·P^T ----
    #pragma unroll
    for (int mt = 0; mt < 4; ++mt) {
      h4 va[4];
      #pragma unroll
      for (int ut = 0; ut < 4; ++ut)
        va[ut] = *(const h4*)(Vc + (ut*16 + n)*VB_STRIDE + mt*32 + quad*8);
      #pragma unroll
      for (int ut = 0; ut < 4; ++ut)
        #pragma unroll
        for (int nt = 0; nt < 2; ++nt)
          O[ut][nt] = MFMA_K16(va[ut], pB[mt][nt], O[ut][nt]);
      #pragma unroll
      for (int nt = 0; nt < 2; ++nt)
        Ol[nt] = MFMA_K16(ones_a, pB[mt][nt], Ol[nt]);
    }

    // ---- stage tile kt+1 into the idle buffer; single barrier ----
    if (more) {
      char* __restrict__ Kn = Ks[cur ^ 1];
      char* __restrict__ Vn = Vs[cur ^ 1];
      *(h8*)(Kn+kofs0) = pk0;  *(h8*)(Kn+kofs1) = pk1;
      *(h8*)(Vn+kofs0) = pv0;  *(h8*)(Vn+kofs1) = pv1;
      __syncthreads();
    }
  }

  // ---- epilogue: f16 partials; every lane holds its own l in Ol ----
  const size_t rowg = (size_t)sp*BS + (size_t)b*SEQ + qbase;
  #pragma unroll
  for (int nt = 0; nt < 2; ++nt) {
    char* __restrict__ orow = (char*)(opart + (rowg + nt*16 + n)*UDIM);
    #pragma unroll
    for (int ut = 0; ut < 4; ++ut)
      #pragma unroll
      for (int p = 0; p < 2; ++p)
        *(unsigned*)(orow + (ut*16 + quad*4 + 2*p)*2) =
            __builtin_bit_cast(unsigned, pk2(O[ut][nt][2*p], O[ut][nt][2*p+1]));
    if (quad == 0) {
      Mp[rowg + nt*16 + n] = M[nt] * L2E;   // log2 domain
      Lp[rowg + nt*16 + n] = Ol[nt][0];
    }
  }
}

// ---------------- Kernel C: merge key-split partials ----------------
__global__ __launch_bounds__(256) void merge_out(
    const _Float16* __restrict__ opart, const float* __restrict__ Mp,
    const float* __restrict__ Lp, float* __restrict__ out, int nsplit)
{
  const int tid = threadIdx.x;
  const int row = blockIdx.x*16 + (tid >> 4);
  const int u4  = (tid & 15) * 4;
  float M = -1e30f;
  for (int s = 0; s < nsplit; ++s) M = fmaxf(M, Mp[(size_t)s*BS + row]);
  f4 num = (f4){0.f,0.f,0.f,0.f};
  float den = 0.f;
  for (int s = 0; s < nsplit; ++s) {
    const float w = exp2f(Mp[(size_t)s*BS + row] - M);
    den += w * Lp[(size_t)s*BS + row];
    const h4 op = *(const h4*)(opart + ((size_t)s*BS + row)*UDIM + u4);
    #pragma unroll
    for (int i = 0; i < 4; ++i) num[i] += w * (float)op[i];
  }
  const float dinv = 1.f / den;
  *(f4*)(out + (size_t)row*UDIM + u4) = num * dinv;
}

extern "C" void kernel_launch(void* const* d_in, const int* in_sizes, int n_in,
                              void* d_out, int out_size, void* d_ws, size_t ws_size,
                              hipStream_t stream) {
  (void)in_sizes; (void)n_in; (void)out_size;
  const float* x  = (const float*)d_in[0];
  const float* Wq = (const float*)d_in[1];
  const float* bq = (const float*)d_in[2];
  const float* Wk = (const float*)d_in[3];
  const float* bk = (const float*)d_in[4];
  const float* Wv = (const float*)d_in[5];
  const float* bv = (const float*)d_in[6];
  float* out = (float*)d_out;

  char* ws = (char*)d_ws;
  const size_t fBytes = (size_t)BS * UDIM * 2;
  auto need = [](int nsp) {   // qkv f16 + Mp/Lp f32 + opart f16
    return (size_t)3*BS*UDIM*2 + (size_t)nsp*BS*4*2 + (size_t)nsp*BS*UDIM*2;
  };
  int nsplit;
  if      (ws_size >= need(8)) nsplit = 8;
  else if (ws_size >= need(4)) nsplit = 4;
  else if (ws_size >= need(2)) nsplit = 2;
  else                         nsplit = 1;

  _Float16* qf = (_Float16*)(ws);
  _Float16* kf = (_Float16*)(ws + fBytes);
  _Float16* vt = (_Float16*)(ws + 2*fBytes);
  float* Mp    = (float*)(ws + 3*fBytes);
  float* Lp    = (float*)(ws + 3*fBytes + (size_t)nsplit*BS*4);
  _Float16* opart = (_Float16*)(ws + 3*fBytes + (size_t)nsplit*BS*8);

  proj_mfma<<<dim3(BS/64, 3), 256, 0, stream>>>(x, Wq, bq, Wk, bk, Wv, bv, qf, kf, vt);
  flash_attn_t<<<dim3(SEQ/128, BATCH, nsplit), 256, 0, stream>>>(
      qf, kf, vt, opart, Mp, Lp, (SEQ/64)/nsplit);
  merge_out<<<dim3(BS/16), 256, 0, stream>>>(opart, Mp, Lp, out, nsplit);
}